// Round 1
// baseline (1710.698 us; speedup 1.0000x reference)
//
#include <hip/hip_runtime.h>
#include <hip/hip_bf16.h>

#define S_LEN 4096
#define NH 4
#define HD 256
#define WIN 512
#define ATT_SCALE 0.0625f   // 256^-0.5

// ---------------------------------------------------------------------------
// Generic fp32 tiled GEMM: C[M,N] = A[M,K] @ B[K,N]
// Requires M%64==0, N%64==0, K%16==0 (all shapes here satisfy this).
// 64x64 tile, BK=16, 256 threads, 4x4 micro-tile per thread.
// ---------------------------------------------------------------------------
__global__ __launch_bounds__(256) void sgemm64(const float* __restrict__ A,
                                               const float* __restrict__ B,
                                               float* __restrict__ C,
                                               int M, int N, int K) {
  __shared__ float As[16][64];   // [k][m]
  __shared__ float Bs[16][64];   // [k][n]
  const int tid = threadIdx.x;
  const int bm = blockIdx.y, bn = blockIdx.x;
  const int ty = tid >> 4, tx = tid & 15;
  const int arow = tid >> 2, acol = (tid & 3) << 2;   // A tile: 64 rows x 16 k
  const int brow = tid >> 4, bcol = (tid & 15) << 2;  // B tile: 16 k x 64 cols
  const float* Ab = A + (size_t)bm * 64 * K;
  const float* Bb = B + (size_t)bn * 64;
  float acc[4][4] = {};
  for (int kt = 0; kt < K; kt += 16) {
    const float4 av = *(const float4*)(Ab + (size_t)arow * K + kt + acol);
    const float4 bv = *(const float4*)(Bb + (size_t)(kt + brow) * N + bcol);
    As[acol + 0][arow] = av.x;
    As[acol + 1][arow] = av.y;
    As[acol + 2][arow] = av.z;
    As[acol + 3][arow] = av.w;
    *(float4*)&Bs[brow][bcol] = bv;
    __syncthreads();
#pragma unroll
    for (int kk = 0; kk < 16; ++kk) {
      const float4 a4 = *(const float4*)&As[kk][ty << 2];
      const float4 b4 = *(const float4*)&Bs[kk][tx << 2];
      const float ar[4] = {a4.x, a4.y, a4.z, a4.w};
      const float br[4] = {b4.x, b4.y, b4.z, b4.w};
#pragma unroll
      for (int r = 0; r < 4; ++r)
#pragma unroll
        for (int c = 0; c < 4; ++c) acc[r][c] += ar[r] * br[c];
    }
    __syncthreads();
  }
#pragma unroll
  for (int r = 0; r < 4; ++r) {
    float4 o;
    o.x = acc[r][0]; o.y = acc[r][1]; o.z = acc[r][2]; o.w = acc[r][3];
    *(float4*)(C + (size_t)(bm * 64 + (ty << 2) + r) * N + bn * 64 + (tx << 2)) = o;
  }
}

// ---------------------------------------------------------------------------
// Fused RMSNorm (over D=256) + interleaved RoPE, in place.
// grid = B*S*5 : h in [0,3] -> q head h ; h==4 -> k row. 256 threads.
// ---------------------------------------------------------------------------
__global__ __launch_bounds__(256) void normrope_kernel(float* __restrict__ q,
                                                       float* __restrict__ k,
                                                       const float* __restrict__ cosb,
                                                       const float* __restrict__ sinb,
                                                       const float* __restrict__ qw,
                                                       const float* __restrict__ kw) {
  const int idx = blockIdx.x;
  const int h = idx % 5;
  const int bs = idx / 5;              // b*S + s
  const int s = bs & (S_LEN - 1);
  float* row;
  const float* w;
  if (h < 4) { row = q + ((size_t)bs * NH + h) * HD; w = qw; }
  else       { row = k + (size_t)bs * HD;            w = kw; }
  const int tid = threadIdx.x;
  const int lane = tid & 63, wave = tid >> 6;
  __shared__ float xs[HD];
  __shared__ float red[4];
  const float xv = row[tid];
  xs[tid] = xv;
  float ssq = xv * xv;
#pragma unroll
  for (int off = 32; off > 0; off >>= 1) ssq += __shfl_xor(ssq, off);
  if (lane == 0) red[wave] = ssq;
  __syncthreads();
  const float tot = red[0] + red[1] + red[2] + red[3];
  const float inv = rsqrtf(tot * (1.0f / 256.0f) + 1e-6f);
  const int pi = tid >> 1;
  const float c = cosb[s * (HD / 2) + pi];
  const float sn = sinb[s * (HD / 2) + pi];
  const float a = xs[pi * 2]     * inv * (1.0f + w[pi * 2]);
  const float b = xs[pi * 2 + 1] * inv * (1.0f + w[pi * 2 + 1]);
  row[tid] = (tid & 1) ? (a * sn + b * c) : (a * c - b * sn);
}

// ---------------------------------------------------------------------------
// Sliding-window causal MQA, one block (256 thr) per (b, i, h).
// blockIdx.x = (b*S + i)*NH + h. Keys j in [max(0,i-512), i].
// ---------------------------------------------------------------------------
__global__ __launch_bounds__(256) void attn_kernel(const float* __restrict__ q,
                                                   const float* __restrict__ k,
                                                   const float* __restrict__ v,
                                                   float* __restrict__ ao) {
  const int idx = blockIdx.x;
  const int h = idx & (NH - 1);
  const int bi = idx >> 2;             // b*S + i
  const int i = bi & (S_LEN - 1);
  const int jmin = max(0, i - WIN);
  const int L = i - jmin + 1;          // <= 513
  const int tid = threadIdx.x;
  const int wave = tid >> 6, lane = tid & 63;
  __shared__ float qs[HD];
  __shared__ float ss[WIN + 1];
  __shared__ float redA[4], redB[4];
  qs[tid] = q[((size_t)bi * NH + h) * HD + tid] * ATT_SCALE;
  __syncthreads();
  const size_t kvbase = (size_t)(bi - i + jmin) * HD;   // (b*S + jmin) * HD
  const float* kb = k + kvbase;
  const float4 qv = *(const float4*)&qs[lane << 2];     // loop-invariant
  for (int jj = wave; jj < L; jj += 4) {
    const float4 kv = *(const float4*)(kb + (size_t)jj * HD + (lane << 2));
    float p = kv.x * qv.x + kv.y * qv.y + kv.z * qv.z + kv.w * qv.w;
#pragma unroll
    for (int off = 32; off > 0; off >>= 1) p += __shfl_xor(p, off);
    if (lane == 0) ss[jj] = p;
  }
  __syncthreads();
  // stable softmax over ss[0..L)
  float m = -3.0e38f;
  for (int t = tid; t < L; t += 256) m = fmaxf(m, ss[t]);
#pragma unroll
  for (int off = 32; off > 0; off >>= 1) m = fmaxf(m, __shfl_xor(m, off));
  if (lane == 0) redA[wave] = m;
  __syncthreads();
  m = fmaxf(fmaxf(redA[0], redA[1]), fmaxf(redA[2], redA[3]));
  float lsum = 0.f;
  for (int t = tid; t < L; t += 256) {
    const float p = expf(ss[t] - m);
    ss[t] = p;
    lsum += p;
  }
#pragma unroll
  for (int off = 32; off > 0; off >>= 1) lsum += __shfl_xor(lsum, off);
  if (lane == 0) redB[wave] = lsum;
  __syncthreads();
  const float inv = 1.0f / (redB[0] + redB[1] + redB[2] + redB[3]);
  // PV: thread = output dim, coalesced v reads
  const float* vb = v + kvbase;
  float acc = 0.f;
  for (int jj = 0; jj < L; ++jj) acc += ss[jj] * vb[(size_t)jj * HD + tid];
  ao[((size_t)bi * NH + h) * HD + tid] = acc * inv;
}

// ---------------------------------------------------------------------------
extern "C" void kernel_launch(void* const* d_in, const int* in_sizes, int n_in,
                              void* d_out, int out_size, void* d_ws, size_t ws_size,
                              hipStream_t stream) {
  const float* x    = (const float*)d_in[0];   // (2,4096,640)
  const float* cosb = (const float*)d_in[1];   // (4096,128)
  const float* sinb = (const float*)d_in[2];   // (4096,128)
  const float* Wq   = (const float*)d_in[3];   // (640,1024)
  const float* Wk   = (const float*)d_in[4];   // (640,256)
  const float* Wv   = (const float*)d_in[5];   // (640,256)
  const float* Wo   = (const float*)d_in[6];   // (1024,640)
  const float* qw   = (const float*)d_in[7];   // (256,)
  const float* kw   = (const float*)d_in[8];   // (256,)
  float* out = (float*)d_out;                  // (2,4096,640)

  float* ws = (float*)d_ws;
  float* q  = ws;                    // 8192*1024 = 8388608 floats
  float* k  = ws + 8388608;          // 8192*256  = 2097152
  float* v  = ws + 10485760;         // 8192*256  = 2097152
  float* ao = ws + 12582912;         // 8192*1024 = 8388608
  const int M = 2 * S_LEN;           // 8192

  // 1) projections
  sgemm64<<<dim3(1024 / 64, M / 64), 256, 0, stream>>>(x, Wq, q, M, 1024, 640);
  sgemm64<<<dim3(256 / 64,  M / 64), 256, 0, stream>>>(x, Wk, k, M, 256, 640);
  sgemm64<<<dim3(256 / 64,  M / 64), 256, 0, stream>>>(x, Wv, v, M, 256, 640);
  // 2) rmsnorm + rope (q heads and k), in place
  normrope_kernel<<<M * 5, 256, 0, stream>>>(q, k, cosb, sinb, qw, kw);
  // 3) sliding-window attention
  attn_kernel<<<M * NH, 256, 0, stream>>>(q, k, v, ao);
  // 4) output projection
  sgemm64<<<dim3(640 / 64, M / 64), 256, 0, stream>>>(ao, Wo, out, M, 640, 1024);
}

// Round 2
// 560.384 us; speedup vs baseline: 3.0527x; 3.0527x over previous
//
#include <hip/hip_runtime.h>
#include <hip/hip_bf16.h>

#define S_LEN 4096
#define NH 4
#define HD 256
#define WIN 512
#define ATT_SCALE 0.0625f   // 256^-0.5

typedef short s16x8 __attribute__((ext_vector_type(8)));
typedef float f32x4 __attribute__((ext_vector_type(4)));

static __device__ inline unsigned short f2bf(float f) {
  union { float f; unsigned int u; } v; v.f = f;
  unsigned int r = v.u + 0x7fff + ((v.u >> 16) & 1);   // RNE
  return (unsigned short)(r >> 16);
}

// ---------------------------------------------------------------------------
// fp32 tiled GEMM: C[M,N] = A[M,K] @ B[K,N]. M%64==0, N%64==0, K%16==0.
// ---------------------------------------------------------------------------
__global__ __launch_bounds__(256) void sgemm64(const float* __restrict__ A,
                                               const float* __restrict__ B,
                                               float* __restrict__ C,
                                               int M, int N, int K) {
  __shared__ float As[16][64];
  __shared__ float Bs[16][64];
  const int tid = threadIdx.x;
  const int bm = blockIdx.y, bn = blockIdx.x;
  const int ty = tid >> 4, tx = tid & 15;
  const int arow = tid >> 2, acol = (tid & 3) << 2;
  const int brow = tid >> 4, bcol = (tid & 15) << 2;
  const float* Ab = A + (size_t)bm * 64 * K;
  const float* Bb = B + (size_t)bn * 64;
  float acc[4][4] = {};
  for (int kt = 0; kt < K; kt += 16) {
    const float4 av = *(const float4*)(Ab + (size_t)arow * K + kt + acol);
    const float4 bv = *(const float4*)(Bb + (size_t)(kt + brow) * N + bcol);
    As[acol + 0][arow] = av.x;
    As[acol + 1][arow] = av.y;
    As[acol + 2][arow] = av.z;
    As[acol + 3][arow] = av.w;
    *(float4*)&Bs[brow][bcol] = bv;
    __syncthreads();
#pragma unroll
    for (int kk = 0; kk < 16; ++kk) {
      const float4 a4 = *(const float4*)&As[kk][ty << 2];
      const float4 b4 = *(const float4*)&Bs[kk][tx << 2];
      const float ar[4] = {a4.x, a4.y, a4.z, a4.w};
      const float br[4] = {b4.x, b4.y, b4.z, b4.w};
#pragma unroll
      for (int r = 0; r < 4; ++r)
#pragma unroll
        for (int c = 0; c < 4; ++c) acc[r][c] += ar[r] * br[c];
    }
    __syncthreads();
  }
#pragma unroll
  for (int r = 0; r < 4; ++r) {
    float4 o;
    o.x = acc[r][0]; o.y = acc[r][1]; o.z = acc[r][2]; o.w = acc[r][3];
    *(float4*)(C + (size_t)(bm * 64 + (ty << 2) + r) * N + bn * 64 + (tx << 2)) = o;
  }
}

// ---------------------------------------------------------------------------
// Fused RMSNorm + RoPE; emits bf16 q (pre-scaled by ATT_SCALE) and bf16 k.
// grid = B*S*5 : h in [0,3] -> q head h ; h==4 -> k row. 256 threads.
// ---------------------------------------------------------------------------
__global__ __launch_bounds__(256) void normrope_kernel(
    const float* __restrict__ q, const float* __restrict__ k,
    const float* __restrict__ cosb, const float* __restrict__ sinb,
    const float* __restrict__ qw, const float* __restrict__ kw,
    unsigned short* __restrict__ qb, unsigned short* __restrict__ kb) {
  const int idx = blockIdx.x;
  const int h = idx % 5;
  const int bs = idx / 5;
  const int s = bs & (S_LEN - 1);
  const float* row; const float* w; unsigned short* dst; float oscale;
  if (h < 4) {
    row = q + ((size_t)bs * NH + h) * HD; w = qw;
    dst = qb + ((size_t)bs * NH + h) * HD; oscale = ATT_SCALE;
  } else {
    row = k + (size_t)bs * HD; w = kw;
    dst = kb + (size_t)bs * HD; oscale = 1.0f;
  }
  const int tid = threadIdx.x;
  const int lane = tid & 63, wave = tid >> 6;
  __shared__ float xs[HD];
  __shared__ float red[4];
  const float xv = row[tid];
  xs[tid] = xv;
  float ssq = xv * xv;
#pragma unroll
  for (int off = 32; off > 0; off >>= 1) ssq += __shfl_xor(ssq, off);
  if (lane == 0) red[wave] = ssq;
  __syncthreads();
  const float tot = red[0] + red[1] + red[2] + red[3];
  const float inv = rsqrtf(tot * (1.0f / 256.0f) + 1e-6f);
  const int pi = tid >> 1;
  const float c = cosb[s * (HD / 2) + pi];
  const float sn = sinb[s * (HD / 2) + pi];
  const float a = xs[pi * 2]     * inv * (1.0f + w[pi * 2]);
  const float b = xs[pi * 2 + 1] * inv * (1.0f + w[pi * 2 + 1]);
  const float outv = ((tid & 1) ? (a * sn + b * c) : (a * c - b * sn)) * oscale;
  dst[tid] = f2bf(outv);
}

// ---------------------------------------------------------------------------
// V transpose + bf16 cast, tile-blocked: vtb[b][jt][d][jj] = v[b][jt*32+jj][d]
// grid = 2*128 blocks, 256 threads.
// ---------------------------------------------------------------------------
__global__ __launch_bounds__(256) void vtranspose_kernel(
    const float* __restrict__ v, unsigned short* __restrict__ vtb) {
  __shared__ float ts[32][260];
  const int b = blockIdx.x >> 7, jt = blockIdx.x & 127;
  const int tid = threadIdx.x;
  const float* src = v + ((size_t)b * S_LEN + jt * 32) * HD;
#pragma unroll
  for (int it = 0; it < 8; ++it) {
    const int c = tid + 256 * it;
    const int row = c >> 6, col4 = (c & 63) << 2;
    *(float4*)&ts[row][col4] = *(const float4*)(src + (size_t)row * HD + col4);
  }
  __syncthreads();
  unsigned short tmp[32];
#pragma unroll
  for (int jj = 0; jj < 32; ++jj) tmp[jj] = f2bf(ts[jj][tid]);
  unsigned short* dst = vtb + ((size_t)(b * 128 + jt) * 256 + tid) * 32;
#pragma unroll
  for (int wq = 0; wq < 4; ++wq) *(uint4*)(dst + wq * 8) = *(uint4*)(tmp + wq * 8);
}

// ---------------------------------------------------------------------------
// Flash-style sliding-window MQA with bf16 MFMA.
// Block = (b, h, 64-row q-tile); 256 thr = 4 waves; wave owns 16 q-rows.
// mfma_f32_16x16x32_bf16: A[m=lane&15][k=(lane>>4)*8+j], B[k][n=lane&15],
// C/D: col=lane&15, row=(lane>>4)*4+reg (m89-verified).
// ---------------------------------------------------------------------------
#define KS_LD 264   // 32x256 K-tile, padded (528B rows: 16B-aligned, 2-way banks)
#define VT_LD 40    // 256x32 Vt-tile, padded (80B rows)
#define PS_LD 40    // 16x32 P per wave, padded

__global__ __launch_bounds__(256) void attn_mfma_kernel(
    const unsigned short* __restrict__ qb, const unsigned short* __restrict__ kb,
    const unsigned short* __restrict__ vtb, float* __restrict__ ao) {
  const int h = blockIdx.x & 3;
  const int qtg = blockIdx.x >> 2;       // 0..127
  const int b = qtg >> 6;
  const int q0 = (qtg & 63) << 6;        // batch-local q row base
  const int tid = threadIdx.x;
  const int wave = tid >> 6;
  const int lane = tid & 63;
  const int ln15 = lane & 15;
  const int lgr = lane >> 4;             // 0..3

  __shared__ unsigned short Ks[32 * KS_LD];
  __shared__ unsigned short Vts[256 * VT_LD];
  __shared__ unsigned short Ps[4][16 * PS_LD];

  // Q fragments in registers: wave's rows = q0 + wave*16 + m (m = ln15)
  const size_t qrow = ((size_t)(b * S_LEN + q0 + wave * 16 + ln15) * NH + h) * HD;
  s16x8 qfrag[8];
#pragma unroll
  for (int f = 0; f < 8; ++f)
    qfrag[f] = *(const s16x8*)(qb + qrow + f * 32 + lgr * 8);

  f32x4 acc[16];
#pragma unroll
  for (int t = 0; t < 16; ++t) acc[t] = (f32x4){0.f, 0.f, 0.f, 0.f};
  float m_prev[4] = {-1e30f, -1e30f, -1e30f, -1e30f};
  float l_run[4]  = {0.f, 0.f, 0.f, 0.f};

  const int kt_lo = max(0, q0 - WIN) >> 5;
  const int kt_hi = (q0 + 63) >> 5;
  const unsigned short* kbase = kb + (size_t)b * S_LEN * HD;
  const unsigned short* vbase = vtb + (size_t)b * (S_LEN / 32) * HD * 32;

  for (int kt = kt_lo; kt <= kt_hi; ++kt) {
    { // stage K tile (32x256) and Vt tile (256x32)
      const unsigned short* src = kbase + (size_t)kt * 32 * HD;
#pragma unroll
      for (int it = 0; it < 4; ++it) {
        const int c = tid + 256 * it;
        const int row = c >> 5, col8 = (c & 31) << 3;
        *(uint4*)&Ks[row * KS_LD + col8] = *(const uint4*)(src + row * HD + col8);
      }
      const unsigned short* vsrc = vbase + (size_t)kt * HD * 32;
#pragma unroll
      for (int it = 0; it < 4; ++it) {
        const int c = tid + 256 * it;
        const int row = c >> 2, col8 = (c & 3) << 3;
        *(uint4*)&Vts[row * VT_LD + col8] = *(const uint4*)(vsrc + c * 8);
      }
    }
    __syncthreads();

    // QK^T: per-wave S tile 16x32 (2 col-tiles of 16)
    f32x4 sc[2];
    sc[0] = (f32x4){0.f, 0.f, 0.f, 0.f};
    sc[1] = (f32x4){0.f, 0.f, 0.f, 0.f};
#pragma unroll
    for (int f = 0; f < 8; ++f) {
#pragma unroll
      for (int ct = 0; ct < 2; ++ct) {
        const s16x8 kf = *(const s16x8*)&Ks[(ct * 16 + ln15) * KS_LD + f * 32 + lgr * 8];
        sc[ct] = __builtin_amdgcn_mfma_f32_16x16x32_bf16(qfrag[f], kf, sc[ct], 0, 0, 0);
      }
    }

    // mask + online softmax (rows wave-internal; 16-lane groups hold rows)
    const int i_row0 = q0 + wave * 16 + lgr * 4;
    float pv[2][4], rm[4];
#pragma unroll
    for (int r = 0; r < 4; ++r) {
      const int i = i_row0 + r;
#pragma unroll
      for (int ct = 0; ct < 2; ++ct) {
        const int j = kt * 32 + ct * 16 + ln15;
        float s = sc[ct][r];
        if (j > i || (i - j) > WIN) s = -1e30f;
        pv[ct][r] = s;
      }
      rm[r] = fmaxf(pv[0][r], pv[1][r]);
    }
#pragma unroll
    for (int off = 1; off < 16; off <<= 1)
#pragma unroll
      for (int r = 0; r < 4; ++r) rm[r] = fmaxf(rm[r], __shfl_xor(rm[r], off));

    float alpha[4], rs[4];
#pragma unroll
    for (int r = 0; r < 4; ++r) {
      const float mn = fmaxf(m_prev[r], rm[r]);
      alpha[r] = __expf(m_prev[r] - mn);
      m_prev[r] = mn;
      const float p0 = __expf(pv[0][r] - mn);
      const float p1 = __expf(pv[1][r] - mn);
      pv[0][r] = p0; pv[1][r] = p1;
      rs[r] = p0 + p1;
    }
#pragma unroll
    for (int off = 1; off < 16; off <<= 1)
#pragma unroll
      for (int r = 0; r < 4; ++r) rs[r] += __shfl_xor(rs[r], off);
#pragma unroll
    for (int r = 0; r < 4; ++r) l_run[r] = l_run[r] * alpha[r] + rs[r];

#pragma unroll
    for (int t = 0; t < 16; ++t)
#pragma unroll
      for (int r = 0; r < 4; ++r) acc[t][r] *= alpha[r];

    // P -> LDS (wave-private), then PV
    unsigned short* psw = Ps[wave];
#pragma unroll
    for (int r = 0; r < 4; ++r) {
      psw[(lgr * 4 + r) * PS_LD + ln15]      = f2bf(pv[0][r]);
      psw[(lgr * 4 + r) * PS_LD + 16 + ln15] = f2bf(pv[1][r]);
    }
    __syncthreads();   // P visibility (and keeps waves loosely in phase)

    const s16x8 pf = *(const s16x8*)&psw[ln15 * PS_LD + lgr * 8];
#pragma unroll
    for (int t = 0; t < 16; ++t) {
      const s16x8 vf = *(const s16x8*)&Vts[(t * 16 + ln15) * VT_LD + lgr * 8];
      acc[t] = __builtin_amdgcn_mfma_f32_16x16x32_bf16(pf, vf, acc[t], 0, 0, 0);
    }
    __syncthreads();   // before next tile's staging overwrites Ks/Vts
  }

  float inv_l[4];
#pragma unroll
  for (int r = 0; r < 4; ++r) inv_l[r] = 1.0f / l_run[r];
#pragma unroll
  for (int t = 0; t < 16; ++t)
#pragma unroll
    for (int r = 0; r < 4; ++r) {
      const size_t orow = (size_t)(b * S_LEN + q0 + wave * 16 + lgr * 4 + r);
      ao[(orow * NH + h) * HD + t * 16 + ln15] = acc[t][r] * inv_l[r];
    }
}

// ---------------------------------------------------------------------------
extern "C" void kernel_launch(void* const* d_in, const int* in_sizes, int n_in,
                              void* d_out, int out_size, void* d_ws, size_t ws_size,
                              hipStream_t stream) {
  const float* x    = (const float*)d_in[0];
  const float* cosb = (const float*)d_in[1];
  const float* sinb = (const float*)d_in[2];
  const float* Wq   = (const float*)d_in[3];
  const float* Wk   = (const float*)d_in[4];
  const float* Wv   = (const float*)d_in[5];
  const float* Wo   = (const float*)d_in[6];
  const float* qw   = (const float*)d_in[7];
  const float* kw   = (const float*)d_in[8];
  float* out = (float*)d_out;

  float* ws = (float*)d_ws;
  float* q   = ws;                        // 8388608 f (reused as ao after normrope)
  float* k   = ws + 8388608;              // 2097152 f
  float* v   = ws + 10485760;             // 2097152 f
  unsigned short* qb  = (unsigned short*)(ws + 12582912);  // 8388608 u16
  unsigned short* kb  = (unsigned short*)(ws + 16777216);  // 2097152 u16
  unsigned short* vtb = (unsigned short*)(ws + 17825792);  // 2097152 u16
  float* ao = q;                          // reuse (q fp32 dead after normrope)
  const int M = 2 * S_LEN;

  sgemm64<<<dim3(1024 / 64, M / 64), 256, 0, stream>>>(x, Wq, q, M, 1024, 640);
  sgemm64<<<dim3(256 / 64,  M / 64), 256, 0, stream>>>(x, Wk, k, M, 256, 640);
  sgemm64<<<dim3(256 / 64,  M / 64), 256, 0, stream>>>(x, Wv, v, M, 256, 640);
  normrope_kernel<<<M * 5, 256, 0, stream>>>(q, k, cosb, sinb, qw, kw, qb, kb);
  vtranspose_kernel<<<256, 256, 0, stream>>>(v, vtb);
  attn_mfma_kernel<<<M / 64 * NH, 256, 0, stream>>>(qb, kb, vtb, ao);
  sgemm64<<<dim3(640 / 64, M / 64), 256, 0, stream>>>(ao, Wo, out, M, 640, 1024);
}

// Round 3
// 244.485 us; speedup vs baseline: 6.9972x; 2.2921x over previous
//
#include <hip/hip_runtime.h>
#include <hip/hip_bf16.h>

#define S_LEN 4096
#define NH 4
#define HD 256
#define WIN 512
#define ATT_SCALE 0.0625f   // 256^-0.5
#define QKV_N 1536          // packed q(1024) | k(256) | v(256)

typedef short s16x8 __attribute__((ext_vector_type(8)));
typedef float f32x4 __attribute__((ext_vector_type(4)));

static __device__ inline unsigned short f2bf(float f) {
  union { float f; unsigned int u; } v; v.f = f;
  unsigned int r = v.u + 0x7fff + ((v.u >> 16) & 1);   // RNE
  return (unsigned short)(r >> 16);
}
static __device__ inline float bf2f(unsigned short h) {
  union { unsigned int u; float f; } v; v.u = ((unsigned int)h) << 16;
  return v.f;
}
static __device__ inline void gl2lds16(const void* g, void* l) {
  __builtin_amdgcn_global_load_lds(
      (const __attribute__((address_space(1))) unsigned int*)g,
      (__attribute__((address_space(3))) unsigned int*)l, 16, 0, 0);
}

// ---------------------------------------------------------------------------
// x (fp32) -> bf16, packed uint2 stores. n4 = n/4.
// ---------------------------------------------------------------------------
__global__ __launch_bounds__(256) void cvt_bf16_kernel(const float* __restrict__ src,
                                                       unsigned short* __restrict__ dst,
                                                       int n4) {
  const int t = blockIdx.x * 256 + threadIdx.x;
  if (t >= n4) return;
  const float4 v = ((const float4*)src)[t];
  const unsigned int p0 = f2bf(v.x) | ((unsigned int)f2bf(v.y) << 16);
  const unsigned int p1 = f2bf(v.z) | ((unsigned int)f2bf(v.w) << 16);
  *(uint2*)(dst + (size_t)t * 4) = make_uint2(p0, p1);
}

// ---------------------------------------------------------------------------
// Transpose + cast: dst[n*K + k] = bf16(src[k*N + n]).  K,N multiples of 64.
// grid = (N/64, K/64), 256 threads, LDS-tiled.
// ---------------------------------------------------------------------------
__global__ __launch_bounds__(256) void trcast64_kernel(const float* __restrict__ src,
                                                       unsigned short* __restrict__ dst,
                                                       int K, int N) {
  __shared__ float ts[64][65];
  const int bn = blockIdx.x, bk = blockIdx.y;
  const int tid = threadIdx.x;
#pragma unroll
  for (int it = 0; it < 4; ++it) {
    const int c = it * 256 + tid;            // float4 index in tile
    const int row = c >> 4, col4 = (c & 15) << 2;
    const float4 v = *(const float4*)(src + (size_t)(bk * 64 + row) * N + bn * 64 + col4);
    ts[row][col4 + 0] = v.x; ts[row][col4 + 1] = v.y;
    ts[row][col4 + 2] = v.z; ts[row][col4 + 3] = v.w;
  }
  __syncthreads();
#pragma unroll
  for (int it = 0; it < 4; ++it) {
    const int c = it * 256 + tid;
    const int nrow = c >> 4, kc4 = (c & 15) << 2;
    const unsigned int p0 = f2bf(ts[kc4 + 0][nrow]) | ((unsigned int)f2bf(ts[kc4 + 1][nrow]) << 16);
    const unsigned int p1 = f2bf(ts[kc4 + 2][nrow]) | ((unsigned int)f2bf(ts[kc4 + 3][nrow]) << 16);
    *(uint2*)(dst + (size_t)(bn * 64 + nrow) * K + bk * 64 + kc4) = make_uint2(p0, p1);
  }
}

// ---------------------------------------------------------------------------
// bf16 MFMA GEMM (m97 structure): C[M,N] = A[M,K] @ Bt[N,K]^T.
// 128x128 tile, BK=32, 256 thr = 4 waves (2x2), 4x4 MFMA 16x16x32 per wave.
// M%128==0, N%128==0, K%32==0. C fp32 or bf16.
// ---------------------------------------------------------------------------
template <bool BF16OUT>
__global__ __launch_bounds__(256) void gemm_bt(const unsigned short* __restrict__ A,
                                               const unsigned short* __restrict__ Bt,
                                               void* __restrict__ Cv,
                                               int M, int N, int K) {
  __shared__ unsigned short As[128 * 32];
  __shared__ unsigned short Bs[128 * 32];
  const int tid = threadIdx.x;
  const int wave = tid >> 6, lane = tid & 63;
  const int ln15 = lane & 15, lgr = lane >> 4;
  const int bm = blockIdx.y, bn = blockIdx.x;
  const int wr = wave & 1, wc = wave >> 1;
  const unsigned short* Ab = A + (size_t)bm * 128 * K;
  const unsigned short* Bb = Bt + (size_t)bn * 128 * K;

  f32x4 acc[4][4];
#pragma unroll
  for (int mt = 0; mt < 4; ++mt)
#pragma unroll
    for (int nt = 0; nt < 4; ++nt) acc[mt][nt] = (f32x4){0.f, 0.f, 0.f, 0.f};

  for (int kt = 0; kt < K; kt += 32) {
#pragma unroll
    for (int i = 0; i < 2; ++i) {
      const int c = tid + 256 * i;           // 16B chunk index
      const int row = c >> 2, kc = (c & 3) << 3;
      gl2lds16(Ab + (size_t)row * K + kt + kc, &As[c * 8]);
      gl2lds16(Bb + (size_t)row * K + kt + kc, &Bs[c * 8]);
    }
    __syncthreads();
    s16x8 af[4], bfr[4];
#pragma unroll
    for (int t = 0; t < 4; ++t) {
      af[t]  = *(const s16x8*)&As[(wr * 64 + t * 16 + ln15) * 32 + lgr * 8];
      bfr[t] = *(const s16x8*)&Bs[(wc * 64 + t * 16 + ln15) * 32 + lgr * 8];
    }
#pragma unroll
    for (int mt = 0; mt < 4; ++mt)
#pragma unroll
      for (int nt = 0; nt < 4; ++nt)
        acc[mt][nt] = __builtin_amdgcn_mfma_f32_16x16x32_bf16(af[mt], bfr[nt], acc[mt][nt], 0, 0, 0);
    __syncthreads();
  }

#pragma unroll
  for (int mt = 0; mt < 4; ++mt)
#pragma unroll
    for (int nt = 0; nt < 4; ++nt)
#pragma unroll
      for (int r = 0; r < 4; ++r) {
        const size_t row = bm * 128 + wr * 64 + mt * 16 + lgr * 4 + r;
        const size_t col = bn * 128 + wc * 64 + nt * 16 + ln15;
        if (BF16OUT) ((unsigned short*)Cv)[row * N + col] = f2bf(acc[mt][nt][r]);
        else         ((float*)Cv)[row * N + col] = acc[mt][nt][r];
      }
}

// ---------------------------------------------------------------------------
// Fused RMSNorm + RoPE, in place on packed bf16 qkv (row stride 1536).
// grid = B*S*5 : h in [0,3] -> q head h (scaled by ATT_SCALE); h==4 -> k.
// ---------------------------------------------------------------------------
__global__ __launch_bounds__(256) void normrope_kernel(
    unsigned short* __restrict__ qkv,
    const float* __restrict__ cosb, const float* __restrict__ sinb,
    const float* __restrict__ qw, const float* __restrict__ kw) {
  const int idx = blockIdx.x;
  const int h = idx % 5;
  const int bs = idx / 5;
  const int s = bs & (S_LEN - 1);
  unsigned short* base = qkv + (size_t)bs * QKV_N;
  unsigned short* row; const float* w; float oscale;
  if (h < 4) { row = base + h * HD;  w = qw; oscale = ATT_SCALE; }
  else       { row = base + 4 * HD;  w = kw; oscale = 1.0f; }
  const int tid = threadIdx.x;
  const int lane = tid & 63, wave = tid >> 6;
  __shared__ float xs[HD];
  __shared__ float red[4];
  const float xv = bf2f(row[tid]);
  xs[tid] = xv;
  float ssq = xv * xv;
#pragma unroll
  for (int off = 32; off > 0; off >>= 1) ssq += __shfl_xor(ssq, off);
  if (lane == 0) red[wave] = ssq;
  __syncthreads();
  const float tot = red[0] + red[1] + red[2] + red[3];
  const float inv = rsqrtf(tot * (1.0f / 256.0f) + 1e-6f);
  const int pi = tid >> 1;
  const float c = cosb[s * (HD / 2) + pi];
  const float sn = sinb[s * (HD / 2) + pi];
  const float a = xs[pi * 2]     * inv * (1.0f + w[pi * 2]);
  const float b = xs[pi * 2 + 1] * inv * (1.0f + w[pi * 2 + 1]);
  const float outv = ((tid & 1) ? (a * sn + b * c) : (a * c - b * sn)) * oscale;
  row[tid] = f2bf(outv);
}

// ---------------------------------------------------------------------------
// V transpose, tile-blocked: vtb[b][jt][d][jj] = v[b][jt*32+jj][d] (bf16 in/out)
// v lives in packed qkv at col offset 1280. grid = 2*128 blocks, 256 threads.
// ---------------------------------------------------------------------------
__global__ __launch_bounds__(256) void vtranspose_kernel(
    const unsigned short* __restrict__ qkv, unsigned short* __restrict__ vtb) {
  __shared__ unsigned short ts[32][264];
  const int b = blockIdx.x >> 7, jt = blockIdx.x & 127;
  const int tid = threadIdx.x;
  const unsigned short* src = qkv + ((size_t)(b * S_LEN) + jt * 32) * QKV_N + 5 * HD;
#pragma unroll
  for (int it = 0; it < 4; ++it) {
    const int c = tid + 256 * it;           // uint4 (8 u16) index
    const int row = c >> 5, col8 = (c & 31) << 3;
    *(uint4*)&ts[row][col8] = *(const uint4*)(src + (size_t)row * QKV_N + col8);
  }
  __syncthreads();
  unsigned short tmp[32];
#pragma unroll
  for (int jj = 0; jj < 32; ++jj) tmp[jj] = ts[jj][tid];
  unsigned short* dst = vtb + ((size_t)(b * 128 + jt) * 256 + tid) * 32;
#pragma unroll
  for (int wq = 0; wq < 4; ++wq) *(uint4*)(dst + wq * 8) = *(uint4*)(tmp + wq * 8);
}

// ---------------------------------------------------------------------------
// Flash-style sliding-window MQA, bf16 MFMA. Block = (b, h, 64-row q-tile).
// q/k read from packed qkv (stride 1536); output bf16.
// ---------------------------------------------------------------------------
#define KS_LD 264
#define VT_LD 40
#define PS_LD 40

__global__ __launch_bounds__(256) void attn_mfma_kernel(
    const unsigned short* __restrict__ qkv, const unsigned short* __restrict__ vtb,
    unsigned short* __restrict__ aob) {
  const int h = blockIdx.x & 3;
  const int qtg = blockIdx.x >> 2;
  const int b = qtg >> 6;
  const int q0 = (qtg & 63) << 6;
  const int tid = threadIdx.x;
  const int wave = tid >> 6;
  const int lane = tid & 63;
  const int ln15 = lane & 15;
  const int lgr = lane >> 4;

  __shared__ unsigned short Ks[32 * KS_LD];
  __shared__ unsigned short Vts[256 * VT_LD];
  __shared__ unsigned short Ps[4][16 * PS_LD];

  const size_t qrow = (size_t)(b * S_LEN + q0 + wave * 16 + ln15) * QKV_N + h * HD;
  s16x8 qfrag[8];
#pragma unroll
  for (int f = 0; f < 8; ++f)
    qfrag[f] = *(const s16x8*)(qkv + qrow + f * 32 + lgr * 8);

  f32x4 acc[16];
#pragma unroll
  for (int t = 0; t < 16; ++t) acc[t] = (f32x4){0.f, 0.f, 0.f, 0.f};
  float m_prev[4] = {-1e30f, -1e30f, -1e30f, -1e30f};
  float l_run[4]  = {0.f, 0.f, 0.f, 0.f};

  const int kt_lo = max(0, q0 - WIN) >> 5;
  const int kt_hi = (q0 + 63) >> 5;
  const unsigned short* kbase = qkv + (size_t)(b * S_LEN) * QKV_N + 4 * HD;
  const unsigned short* vbase = vtb + (size_t)b * (S_LEN / 32) * HD * 32;

  for (int kt = kt_lo; kt <= kt_hi; ++kt) {
    {
      const unsigned short* src = kbase + (size_t)kt * 32 * QKV_N;
#pragma unroll
      for (int it = 0; it < 4; ++it) {
        const int c = tid + 256 * it;
        const int row = c >> 5, col8 = (c & 31) << 3;
        *(uint4*)&Ks[row * KS_LD + col8] = *(const uint4*)(src + (size_t)row * QKV_N + col8);
      }
      const unsigned short* vsrc = vbase + (size_t)kt * HD * 32;
#pragma unroll
      for (int it = 0; it < 4; ++it) {
        const int c = tid + 256 * it;
        const int row = c >> 2, col8 = (c & 3) << 3;
        *(uint4*)&Vts[row * VT_LD + col8] = *(const uint4*)(vsrc + c * 8);
      }
    }
    __syncthreads();

    f32x4 sc[2];
    sc[0] = (f32x4){0.f, 0.f, 0.f, 0.f};
    sc[1] = (f32x4){0.f, 0.f, 0.f, 0.f};
#pragma unroll
    for (int f = 0; f < 8; ++f) {
#pragma unroll
      for (int ct = 0; ct < 2; ++ct) {
        const s16x8 kf = *(const s16x8*)&Ks[(ct * 16 + ln15) * KS_LD + f * 32 + lgr * 8];
        sc[ct] = __builtin_amdgcn_mfma_f32_16x16x32_bf16(qfrag[f], kf, sc[ct], 0, 0, 0);
      }
    }

    const int i_row0 = q0 + wave * 16 + lgr * 4;
    float pv[2][4], rm[4];
#pragma unroll
    for (int r = 0; r < 4; ++r) {
      const int i = i_row0 + r;
#pragma unroll
      for (int ct = 0; ct < 2; ++ct) {
        const int j = kt * 32 + ct * 16 + ln15;
        float s = sc[ct][r];
        if (j > i || (i - j) > WIN) s = -1e30f;
        pv[ct][r] = s;
      }
      rm[r] = fmaxf(pv[0][r], pv[1][r]);
    }
#pragma unroll
    for (int off = 1; off < 16; off <<= 1)
#pragma unroll
      for (int r = 0; r < 4; ++r) rm[r] = fmaxf(rm[r], __shfl_xor(rm[r], off));

    float alpha[4], rs[4];
#pragma unroll
    for (int r = 0; r < 4; ++r) {
      const float mn = fmaxf(m_prev[r], rm[r]);
      alpha[r] = __expf(m_prev[r] - mn);
      m_prev[r] = mn;
      const float p0 = __expf(pv[0][r] - mn);
      const float p1 = __expf(pv[1][r] - mn);
      pv[0][r] = p0; pv[1][r] = p1;
      rs[r] = p0 + p1;
    }
#pragma unroll
    for (int off = 1; off < 16; off <<= 1)
#pragma unroll
      for (int r = 0; r < 4; ++r) rs[r] += __shfl_xor(rs[r], off);
#pragma unroll
    for (int r = 0; r < 4; ++r) l_run[r] = l_run[r] * alpha[r] + rs[r];

#pragma unroll
    for (int t = 0; t < 16; ++t)
#pragma unroll
      for (int r = 0; r < 4; ++r) acc[t][r] *= alpha[r];

    unsigned short* psw = Ps[wave];
#pragma unroll
    for (int r = 0; r < 4; ++r) {
      psw[(lgr * 4 + r) * PS_LD + ln15]      = f2bf(pv[0][r]);
      psw[(lgr * 4 + r) * PS_LD + 16 + ln15] = f2bf(pv[1][r]);
    }
    __syncthreads();

    const s16x8 pf = *(const s16x8*)&psw[ln15 * PS_LD + lgr * 8];
#pragma unroll
    for (int t = 0; t < 16; ++t) {
      const s16x8 vf = *(const s16x8*)&Vts[(t * 16 + ln15) * VT_LD + lgr * 8];
      acc[t] = __builtin_amdgcn_mfma_f32_16x16x32_bf16(pf, vf, acc[t], 0, 0, 0);
    }
    __syncthreads();
  }

  float inv_l[4];
#pragma unroll
  for (int r = 0; r < 4; ++r) inv_l[r] = 1.0f / l_run[r];
#pragma unroll
  for (int t = 0; t < 16; ++t)
#pragma unroll
    for (int r = 0; r < 4; ++r) {
      const size_t orow = (size_t)(b * S_LEN + q0 + wave * 16 + lgr * 4 + r);
      aob[(orow * NH + h) * HD + t * 16 + ln15] = f2bf(acc[t][r] * inv_l[r]);
    }
}

// ---------------------------------------------------------------------------
extern "C" void kernel_launch(void* const* d_in, const int* in_sizes, int n_in,
                              void* d_out, int out_size, void* d_ws, size_t ws_size,
                              hipStream_t stream) {
  const float* x    = (const float*)d_in[0];
  const float* cosb = (const float*)d_in[1];
  const float* sinb = (const float*)d_in[2];
  const float* Wq   = (const float*)d_in[3];
  const float* Wk   = (const float*)d_in[4];
  const float* Wv   = (const float*)d_in[5];
  const float* Wo   = (const float*)d_in[6];
  const float* qw   = (const float*)d_in[7];
  const float* kw   = (const float*)d_in[8];
  float* out = (float*)d_out;

  unsigned short* ws = (unsigned short*)d_ws;
  unsigned short* xb     = ws;                    // 8192*640  = 5242880
  unsigned short* Wqkvt  = xb + 5242880;          // 1536*640  = 983040
  unsigned short* Wot    = Wqkvt + 983040;        // 640*1024  = 655360
  unsigned short* qkvb   = Wot + 655360;          // 8192*1536 = 12582912
  unsigned short* vtb    = qkvb + 12582912;       // 8192*256  = 2097152
  unsigned short* aob    = vtb + 2097152;         // 8192*1024 = 8388608
  const int M = 2 * S_LEN;                        // total ~60 MB

  // casts / weight packing (transposed)
  cvt_bf16_kernel<<<(M * 640 / 4 + 255) / 256, 256, 0, stream>>>(x, xb, M * 640 / 4);
  trcast64_kernel<<<dim3(1024 / 64, 640 / 64), 256, 0, stream>>>(Wq, Wqkvt, 640, 1024);
  trcast64_kernel<<<dim3(256 / 64, 640 / 64), 256, 0, stream>>>(Wk, Wqkvt + (size_t)1024 * 640, 640, 256);
  trcast64_kernel<<<dim3(256 / 64, 640 / 64), 256, 0, stream>>>(Wv, Wqkvt + (size_t)1280 * 640, 640, 256);
  trcast64_kernel<<<dim3(640 / 64, 1024 / 64), 256, 0, stream>>>(Wo, Wot, 1024, 640);
  // QKV projection (packed) -> bf16
  gemm_bt<true><<<dim3(QKV_N / 128, M / 128), 256, 0, stream>>>(xb, Wqkvt, qkvb, M, QKV_N, 640);
  // rmsnorm + rope in place
  normrope_kernel<<<M * 5, 256, 0, stream>>>(qkvb, cosb, sinb, qw, kw);
  // V transpose tiles
  vtranspose_kernel<<<256, 256, 0, stream>>>(qkvb, vtb);
  // attention
  attn_mfma_kernel<<<M / 64 * NH, 256, 0, stream>>>(qkvb, vtb, aob);
  // output projection -> fp32 out
  gemm_bt<false><<<dim3(640 / 128, M / 128), 256, 0, stream>>>(aob, Wot, out, M, 640, 1024);
}